// Round 1
// baseline (605.702 us; speedup 1.0000x reference)
//
#include <hip/hip_runtime.h>
#include <stdint.h>
#include <math.h>

typedef __attribute__((ext_vector_type(8))) short short8;
typedef __attribute__((ext_vector_type(4))) float f32x4;

struct alignas(8) U16x4 { unsigned short x, y, z, w; };

#define S_LEN 2048
#define NBATCH 32
#define KDIM 1024
#define NDIM 1024
#define MROWS 65536
#define NEG_INF_F (-1e9f)

#define BM 128
#define BN 256
#define BK 32
#define LDT 40  /* padded LDS row stride in ushorts: 32 + 8 */

__device__ __forceinline__ void split2(float x, unsigned short& h, unsigned short& l) {
    union { float f; uint32_t u; } a; a.f = x;
    h = (unsigned short)(a.u >> 16);
    union { float f; uint32_t u; } hf; hf.u = a.u & 0xFFFF0000u;
    union { float f; uint32_t u; } lf; lf.f = x - hf.f;
    l = (unsigned short)(lf.u >> 16);
}

// ---------------------------------------------------------------------------
// dec[b,e] = sum_d dh[b,d] * Ws[e,d]   (one block per e)
// ---------------------------------------------------------------------------
__global__ __launch_bounds__(256) void dec_kernel(
    const float* __restrict__ dh, const float* __restrict__ Ws,
    float* __restrict__ dec)
{
    __shared__ float wrow[1024];
    int e = blockIdx.x;
    int t = threadIdx.x;
    #pragma unroll
    for (int i = t; i < 1024; i += 256) wrow[i] = Ws[(size_t)e * 1024 + i];
    __syncthreads();
    int b = t >> 3, part = t & 7;
    const float* dhp = dh + (size_t)b * 1024 + part * 128;
    const float* wp  = wrow + part * 128;
    float s = 0.f;
    #pragma unroll 8
    for (int i = 0; i < 128; ++i) s += dhp[i] * wp[i];
    s += __shfl_xor(s, 1);
    s += __shfl_xor(s, 2);
    s += __shfl_xor(s, 4);
    if (part == 0) dec[(size_t)b * 1024 + e] = s;
}

// ---------------------------------------------------------------------------
// Fused energy GEMM:
//   enc[m,n] = sum_k A[m,k] * Wh[n,k]   (3-pass bf16 split, fp32 acc)
//   energy[m] += sum_n tanh(enc[m,n] + dec[b,n]) * v[n]   (atomic partial)
// Grid: 2048 blocks (512 M-blocks x 4 N-blocks), 512 threads (8 waves).
// ---------------------------------------------------------------------------
__global__ __launch_bounds__(512) void energy_gemm(
    const float* __restrict__ A,    // [65536,1024] encoder_outputs
    const float* __restrict__ Wh,   // [1024,1024]
    const float* __restrict__ dec,  // [32,1024]
    const float* __restrict__ v,    // [1024]
    float* __restrict__ energy)     // [65536], pre-zeroed
{
    __shared__ unsigned short As_hi[BM * LDT];
    __shared__ unsigned short As_lo[BM * LDT];
    __shared__ unsigned short Bs_hi[BN * LDT];
    __shared__ unsigned short Bs_lo[BN * LDT];

    // XCD-aware swizzle: 2048 blocks = 8 XCDs x 256. Put the 4 N-blocks of
    // each M-block consecutively on the same XCD so the A panel is L2-shared.
    int bid = blockIdx.x;
    int lid = (bid & 7) * 256 + (bid >> 3);
    int mblk = lid >> 2, nblk = lid & 3;
    int m0 = mblk * BM, n0 = nblk * BN;
    int b = m0 / S_LEN;   // BM=128 divides S=2048 -> single batch per block

    int t = threadIdx.x;
    int wid = t >> 6, lane = t & 63;
    int wm = wid >> 2, wn = wid & 3;     // wave grid 2 x 4, wave tile 64 x 64
    int kg = lane >> 4, lr = lane & 15;

    f32x4 acc[4][4] = {};

    for (int k0 = 0; k0 < KDIM; k0 += BK) {
        // ---- stage A (128x32 f32 -> hi/lo bf16) : 2 passes of 512 float4
        #pragma unroll
        for (int p = 0; p < 2; ++p) {
            int idx = t + p * 512;
            int row = idx >> 3, cg = idx & 7;
            f32x4 xv = *(const f32x4*)(A + (size_t)(m0 + row) * KDIM + k0 + cg * 4);
            U16x4 h, l;
            split2(xv.x, h.x, l.x); split2(xv.y, h.y, l.y);
            split2(xv.z, h.z, l.z); split2(xv.w, h.w, l.w);
            *(U16x4*)&As_hi[row * LDT + cg * 4] = h;
            *(U16x4*)&As_lo[row * LDT + cg * 4] = l;
        }
        // ---- stage B (256x32 f32 -> hi/lo bf16) : 4 passes
        #pragma unroll
        for (int p = 0; p < 4; ++p) {
            int idx = t + p * 512;
            int row = idx >> 3, cg = idx & 7;
            f32x4 xv = *(const f32x4*)(Wh + (size_t)(n0 + row) * KDIM + k0 + cg * 4);
            U16x4 h, l;
            split2(xv.x, h.x, l.x); split2(xv.y, h.y, l.y);
            split2(xv.z, h.z, l.z); split2(xv.w, h.w, l.w);
            *(U16x4*)&Bs_hi[row * LDT + cg * 4] = h;
            *(U16x4*)&Bs_lo[row * LDT + cg * 4] = l;
        }
        __syncthreads();

        // ---- fragments: A row = lane%16, k = (lane/16)*8 + i (consistent A/B)
        short8 afh[4], afl[4], bfh[4], bfl[4];
        #pragma unroll
        for (int mi = 0; mi < 4; ++mi) {
            int off = (wm * 64 + mi * 16 + lr) * LDT + kg * 8;
            afh[mi] = *(const short8*)&As_hi[off];
            afl[mi] = *(const short8*)&As_lo[off];
        }
        #pragma unroll
        for (int ni = 0; ni < 4; ++ni) {
            int off = (wn * 64 + ni * 16 + lr) * LDT + kg * 8;
            bfh[ni] = *(const short8*)&Bs_hi[off];
            bfl[ni] = *(const short8*)&Bs_lo[off];
        }
        #pragma unroll
        for (int mi = 0; mi < 4; ++mi)
            #pragma unroll
            for (int ni = 0; ni < 4; ++ni) {
                acc[mi][ni] = __builtin_amdgcn_mfma_f32_16x16x32_bf16(afh[mi], bfh[ni], acc[mi][ni], 0, 0, 0);
                acc[mi][ni] = __builtin_amdgcn_mfma_f32_16x16x32_bf16(afl[mi], bfh[ni], acc[mi][ni], 0, 0, 0);
                acc[mi][ni] = __builtin_amdgcn_mfma_f32_16x16x32_bf16(afh[mi], bfl[ni], acc[mi][ni], 0, 0, 0);
            }
        __syncthreads();
    }

    // ---- epilogue: energy[m] += sum_n tanh(enc + dec) * v
    float vv[4], dd[4];
    #pragma unroll
    for (int ni = 0; ni < 4; ++ni) {
        int d = n0 + wn * 64 + ni * 16 + lr;
        vv[ni] = v[d];
        dd[ni] = dec[(size_t)b * 1024 + d];
    }
    #pragma unroll
    for (int mi = 0; mi < 4; ++mi) {
        #pragma unroll
        for (int r = 0; r < 4; ++r) {
            float local = 0.f;
            #pragma unroll
            for (int ni = 0; ni < 4; ++ni)
                local += tanhf(acc[mi][ni][r] + dd[ni]) * vv[ni];
            // reduce across the 16 lanes (bits 0..3) holding different n
            local += __shfl_xor(local, 1);
            local += __shfl_xor(local, 2);
            local += __shfl_xor(local, 4);
            local += __shfl_xor(local, 8);
            if (lr == 0) {
                int m = m0 + wm * 64 + mi * 16 + kg * 4 + r;
                atomicAdd(&energy[m], local);
            }
        }
    }
}

// ---------------------------------------------------------------------------
// Masked softmax over S per batch row. One block per b.
// ---------------------------------------------------------------------------
__global__ __launch_bounds__(256) void softmax_kernel(
    const float* __restrict__ energy, const int* __restrict__ mask,
    float* __restrict__ attn)
{
    int b = blockIdx.x;
    int t = threadIdx.x;
    int wid = t >> 6, lane = t & 63;
    __shared__ float wmax[4], wsum[4];

    float vals[8];
    float mx = -INFINITY;
    #pragma unroll
    for (int j = 0; j < 8; ++j) {
        int s = t + j * 256;
        float e = energy[(size_t)b * S_LEN + s];
        if (mask[(size_t)b * S_LEN + s] == 0) e = NEG_INF_F;
        vals[j] = e;
        mx = fmaxf(mx, e);
    }
    #pragma unroll
    for (int m = 1; m < 64; m <<= 1) mx = fmaxf(mx, __shfl_xor(mx, m));
    if (lane == 0) wmax[wid] = mx;
    __syncthreads();
    mx = fmaxf(fmaxf(wmax[0], wmax[1]), fmaxf(wmax[2], wmax[3]));

    float sum = 0.f;
    #pragma unroll
    for (int j = 0; j < 8; ++j) { vals[j] = expf(vals[j] - mx); sum += vals[j]; }
    #pragma unroll
    for (int m = 1; m < 64; m <<= 1) sum += __shfl_xor(sum, m);
    if (lane == 0) wsum[wid] = sum;
    __syncthreads();
    sum = wsum[0] + wsum[1] + wsum[2] + wsum[3];
    float inv = 1.f / sum;
    #pragma unroll
    for (int j = 0; j < 8; ++j)
        attn[(size_t)b * S_LEN + t + j * 256] = vals[j] * inv;
}

// ---------------------------------------------------------------------------
// context[b,e] = sum_s attn[b,s] * x[b,s,e]. Grid (4 e-chunks, 32 b, 16 s-chunks).
// ---------------------------------------------------------------------------
__global__ __launch_bounds__(256) void context_kernel(
    const float* __restrict__ attn, const float* __restrict__ x,
    float* __restrict__ ctx)
{
    int ec = blockIdx.x, b = blockIdx.y, sc = blockIdx.z;
    int e = ec * 256 + threadIdx.x;
    const float* xp = x + ((size_t)b * S_LEN + sc * 128) * KDIM + e;
    const float* ap = attn + (size_t)b * S_LEN + sc * 128;
    float acc = 0.f;
    #pragma unroll 4
    for (int s = 0; s < 128; ++s) acc += ap[s] * xp[(size_t)s * KDIM];
    atomicAdd(&ctx[(size_t)b * KDIM + e], acc);
}

// ---------------------------------------------------------------------------
extern "C" void kernel_launch(void* const* d_in, const int* in_sizes, int n_in,
                              void* d_out, int out_size, void* d_ws, size_t ws_size,
                              hipStream_t stream) {
    const float* dh   = (const float*)d_in[0];  // [32,1024]
    const float* x    = (const float*)d_in[1];  // [32,2048,1024]
    const int*   mask = (const int*)d_in[2];    // [32,2048]
    const float* Wh   = (const float*)d_in[3];  // [1024,1024]
    const float* Ws   = (const float*)d_in[4];  // [1024,1024]
    const float* v    = (const float*)d_in[5];  // [1024]

    float* ctx  = (float*)d_out;                 // [32*1024]
    float* attn = (float*)d_out + 32 * 1024;     // [32*2048]
    float* dec    = (float*)d_ws;                // 32768 f32
    float* energy = dec + 32 * 1024;             // 65536 f32

    hipMemsetAsync(energy, 0, (size_t)MROWS / 1 * 0 + 65536 * sizeof(float), stream);
    hipMemsetAsync(ctx, 0, 32768 * sizeof(float), stream);

    dec_kernel<<<1024, 256, 0, stream>>>(dh, Ws, dec);
    energy_gemm<<<2048, 512, 0, stream>>>(x, Wh, dec, v, energy);
    softmax_kernel<<<NBATCH, 256, 0, stream>>>(energy, mask, attn);
    context_kernel<<<dim3(4, NBATCH, 16), 256, 0, stream>>>(attn, x, ctx);
}